// Round 1
// baseline (501.667 us; speedup 1.0000x reference)
//
#include <hip/hip_runtime.h>
#include <hip/hip_bf16.h>

typedef __hip_bfloat16 bf16t;
typedef short bf16x8 __attribute__((ext_vector_type(8)));
typedef float f32x4 __attribute__((ext_vector_type(4)));

__device__ __forceinline__ float b2f(short s) {
    unsigned u = ((unsigned)(unsigned short)s) << 16;
    float f;
    __builtin_memcpy(&f, &u, 4);
    return f;
}

__device__ __forceinline__ unsigned short f2b(float f) {
    unsigned u;
    __builtin_memcpy(&u, &f, 4);
    unsigned r = (u + 0x7fffu + ((u >> 16) & 1u)) >> 16;  // RNE
    return (unsigned short)r;
}

__device__ __forceinline__ void gload_lds16(const void* g, void* l) {
    __builtin_amdgcn_global_load_lds(
        (const __attribute__((address_space(1))) void*)g,
        (__attribute__((address_space(3))) void*)l,
        16, 0, 0);
}

// ---------------------------------------------------------------------------
// NT GEMM: C[M,N] = scale * (A[M,K] @ B[N,K]^T) + bias[N]
// A,B bf16 row-major. m97 structure: 128x128 tile, BK=32, 4 waves (2x2),
// each wave 64x64 via 4x4 fragments of mfma_f32_16x16x32_bf16.
// z-batched with (b,h) offsets: z = b*8 + h.
// EPI: 0 = bf16 out (+optional bias), 1 = fp32 out + bias,
//      2 = bf16 V-transposed write Vt[b,h,dd,ss] (+bias)
// ---------------------------------------------------------------------------
template<int EPI>
__global__ __launch_bounds__(256)
void gemm_nt(const bf16t* __restrict__ Ag, const bf16t* __restrict__ Bg,
             void* __restrict__ Cg, const float* __restrict__ bias,
             int M, int N, int K, int lda, int ldb, int ldc,
             long aOffB, long aOffH, long bOffB, long bOffH,
             long cOffB, long cOffH, float scale)
{
    const int z  = blockIdx.z;
    const int zb = z >> 3, zh = z & 7;
    const char* A  = (const char*)(Ag + (size_t)zb * aOffB + (size_t)zh * aOffH);
    const char* Bp = (const char*)(Bg + (size_t)zb * bOffB + (size_t)zh * bOffH);

    __shared__ bf16t As[128 * 32];
    __shared__ bf16t Bs[128 * 32];

    const int t    = threadIdx.x;
    const int lane = t & 63;
    const int wid  = t >> 6;
    const int wr   = wid >> 1, wc = wid & 1;
    const int brow = blockIdx.y * 128;
    const int bcol = blockIdx.x * 128;
    const int lr   = lane & 15;   // fragment row (A) / col (B/C)
    const int lk   = lane >> 4;   // k-group

    const size_t ldab = (size_t)lda * 2;
    const size_t ldbb = (size_t)ldb * 2;

    f32x4 acc[4][4];
#pragma unroll
    for (int i = 0; i < 4; ++i)
#pragma unroll
        for (int j = 0; j < 4; ++j)
            acc[i][j] = (f32x4){0.f, 0.f, 0.f, 0.f};

    // staging: tile is 128 rows x 64 bytes; 512 chunks of 16B; 256 threads x2
    const int c0 = t, c1 = t + 256;
    const char* Abase = A  + (size_t)brow * ldab;
    const char* Bbase = Bp + (size_t)bcol * ldbb;
    const size_t aSrc0 = (size_t)(c0 >> 2) * ldab + (size_t)(c0 & 3) * 16;
    const size_t aSrc1 = (size_t)(c1 >> 2) * ldab + (size_t)(c1 & 3) * 16;
    const size_t bSrc0 = (size_t)(c0 >> 2) * ldbb + (size_t)(c0 & 3) * 16;
    const size_t bSrc1 = (size_t)(c1 >> 2) * ldbb + (size_t)(c1 & 3) * 16;
    char* AsB = (char*)As;
    char* BsB = (char*)Bs;

    const int nk = K >> 5;
    for (int kt = 0; kt < nk; ++kt) {
        const size_t kOff = (size_t)kt * 64;
        gload_lds16(Abase + aSrc0 + kOff, AsB + (size_t)c0 * 16);
        gload_lds16(Abase + aSrc1 + kOff, AsB + (size_t)c1 * 16);
        gload_lds16(Bbase + bSrc0 + kOff, BsB + (size_t)c0 * 16);
        gload_lds16(Bbase + bSrc1 + kOff, BsB + (size_t)c1 * 16);
        asm volatile("s_waitcnt vmcnt(0)" ::: "memory");
        __syncthreads();

        bf16x8 af[4], bfv[4];
#pragma unroll
        for (int i = 0; i < 4; ++i)
            af[i] = *(const bf16x8*)(AsB + ((size_t)(wr * 64 + i * 16 + lr) * 32 + lk * 8) * 2);
#pragma unroll
        for (int j = 0; j < 4; ++j)
            bfv[j] = *(const bf16x8*)(BsB + ((size_t)(wc * 64 + j * 16 + lr) * 32 + lk * 8) * 2);
#pragma unroll
        for (int i = 0; i < 4; ++i)
#pragma unroll
            for (int j = 0; j < 4; ++j)
                acc[i][j] = __builtin_amdgcn_mfma_f32_16x16x32_bf16(af[i], bfv[j], acc[i][j], 0, 0, 0);
        __syncthreads();
    }

    const int orow = brow + wr * 64;
    const int ocol = bcol + wc * 64;

    if (EPI == 0) {
        unsigned short* C = (unsigned short*)((bf16t*)Cg + (size_t)zb * cOffB + (size_t)zh * cOffH);
#pragma unroll
        for (int i = 0; i < 4; ++i)
#pragma unroll
            for (int j = 0; j < 4; ++j) {
                int col = ocol + j * 16 + lr;
                float badd = bias ? bias[col] : 0.f;
#pragma unroll
                for (int r = 0; r < 4; ++r) {
                    int row = orow + i * 16 + lk * 4 + r;
                    C[(size_t)row * ldc + col] = f2b(acc[i][j][r] * scale + badd);
                }
            }
    } else if (EPI == 1) {
        float* C = (float*)Cg;
#pragma unroll
        for (int i = 0; i < 4; ++i)
#pragma unroll
            for (int j = 0; j < 4; ++j) {
                int col = ocol + j * 16 + lr;
                float badd = bias ? bias[col] : 0.f;
#pragma unroll
                for (int r = 0; r < 4; ++r) {
                    int row = orow + i * 16 + lk * 4 + r;
                    C[(size_t)row * ldc + col] = acc[i][j][r] * scale + badd;
                }
            }
    } else {  // EPI == 2: V transposed write, Vt[((b*8+h)*512+dd)*2048 + ss]
        unsigned short* C = (unsigned short*)Cg;
#pragma unroll
        for (int i = 0; i < 4; ++i)
#pragma unroll
            for (int j = 0; j < 4; ++j) {
                int col = ocol + j * 16 + lr;     // n in [0,4096)
                int hh = col >> 9, dd = col & 511;
                float badd = bias ? bias[col] : 0.f;
                int row0 = orow + i * 16 + lk * 4; // 4 consecutive rows
                int bb = row0 >> 11, ss0 = row0 & 2047;
                ushort4 pack;
                pack.x = f2b(acc[i][j][0] * scale + badd);
                pack.y = f2b(acc[i][j][1] * scale + badd);
                pack.z = f2b(acc[i][j][2] * scale + badd);
                pack.w = f2b(acc[i][j][3] * scale + badd);
                size_t addr = ((((size_t)(bb * 8 + hh)) * 512 + dd) << 11) + (size_t)ss0;
                *(ushort4*)(C + addr) = pack;
            }
    }
}

// ---------------------------------------------------------------------------
// In-place row softmax over 2048 bf16 columns. One block (256 thr) per row.
// ---------------------------------------------------------------------------
__global__ __launch_bounds__(256)
void softmax2048(bf16t* __restrict__ Sp)
{
    size_t row = blockIdx.x;
    bf16x8* p = (bf16x8*)(Sp + row * 2048);
    int t = threadIdx.x;
    bf16x8 raw = p[t];
    float v[8];
    float mx = -3.0e38f;
#pragma unroll
    for (int i = 0; i < 8; ++i) { v[i] = b2f(raw[i]); mx = fmaxf(mx, v[i]); }
#pragma unroll
    for (int off = 1; off < 64; off <<= 1) mx = fmaxf(mx, __shfl_xor(mx, off));
    __shared__ float redm[4], reds[4];
    int wid = t >> 6, lane = t & 63;
    if (lane == 0) redm[wid] = mx;
    __syncthreads();
    mx = fmaxf(fmaxf(redm[0], redm[1]), fmaxf(redm[2], redm[3]));
    float sum = 0.f;
#pragma unroll
    for (int i = 0; i < 8; ++i) { v[i] = __expf(v[i] - mx); sum += v[i]; }
#pragma unroll
    for (int off = 1; off < 64; off <<= 1) sum += __shfl_xor(sum, off);
    if (lane == 0) reds[wid] = sum;
    __syncthreads();
    sum = reds[0] + reds[1] + reds[2] + reds[3];
    float inv = 1.0f / sum;
    bf16x8 o;
#pragma unroll
    for (int i = 0; i < 8; ++i) o[i] = (short)f2b(v[i] * inv);
    p[t] = o;
}

// ---------------------------------------------------------------------------
// fp32 -> bf16 conversion, 4 elements/thread
// ---------------------------------------------------------------------------
__global__ __launch_bounds__(256)
void cvt_f32_bf16(const float* __restrict__ in, bf16t* __restrict__ out, int n4)
{
    int i = blockIdx.x * 256 + threadIdx.x;
    if (i >= n4) return;
    float4 f = ((const float4*)in)[i];
    ushort4 o;
    o.x = f2b(f.x); o.y = f2b(f.y); o.z = f2b(f.z); o.w = f2b(f.w);
    ((ushort4*)out)[i] = o;
}

extern "C" void kernel_launch(void* const* d_in, const int* in_sizes, int n_in,
                              void* d_out, int out_size, void* d_ws, size_t ws_size,
                              hipStream_t stream)
{
    const float* x  = (const float*)d_in[0];
    const float* Wq = (const float*)d_in[1];
    const float* bq = (const float*)d_in[2];
    const float* Wk = (const float*)d_in[3];
    const float* bk = (const float*)d_in[4];
    const float* Wv = (const float*)d_in[5];
    const float* bv = (const float*)d_in[6];
    const float* Wo = (const float*)d_in[7];
    const float* bo = (const float*)d_in[8];

    const int Bn = 2, Sn = 2048, Dn = 512, Hn = 8, En = 4096;
    const int Mn = Bn * Sn;  // 4096
    const float scl = 0.044194173824159216f;  // 1/sqrt(512)

    // workspace layout (bf16 elements)
    bf16t* base = (bf16t*)d_ws;
    size_t off = 0;
    bf16t* Qb  = base + off; off += (size_t)Mn * En;   // Q, later reused as ctx
    bf16t* Kb  = base + off; off += (size_t)Mn * En;
    bf16t* Vt  = base + off; off += (size_t)Mn * En;   // [b,h,512,2048]
    bf16t* Xb  = base + off; off += (size_t)Mn * Dn;
    bf16t* Wqb = base + off; off += (size_t)En * Dn;
    bf16t* Wkb = base + off; off += (size_t)En * Dn;
    bf16t* Wvb = base + off; off += (size_t)En * Dn;
    bf16t* Wob = base + off; off += (size_t)Dn * En;
    bf16t* Sb  = base + off;
    const size_t sAll = (size_t)Bn * Hn * Sn * Sn;
    const bool batched = ws_size >= (off + sAll) * sizeof(bf16t);

    // fp32 -> bf16
    {
        size_t nX = (size_t)Mn * Dn, nW = (size_t)En * Dn;
        cvt_f32_bf16<<<(int)(nX / 4 / 256), 256, 0, stream>>>(x,  Xb,  (int)(nX / 4));
        cvt_f32_bf16<<<(int)(nW / 4 / 256), 256, 0, stream>>>(Wq, Wqb, (int)(nW / 4));
        cvt_f32_bf16<<<(int)(nW / 4 / 256), 256, 0, stream>>>(Wk, Wkb, (int)(nW / 4));
        cvt_f32_bf16<<<(int)(nW / 4 / 256), 256, 0, stream>>>(Wv, Wvb, (int)(nW / 4));
        cvt_f32_bf16<<<(int)(nW / 4 / 256), 256, 0, stream>>>(Wo, Wob, (int)(nW / 4));
    }

    // QKV projections
    gemm_nt<0><<<dim3(En / 128, Mn / 128, 1), 256, 0, stream>>>(
        Xb, Wqb, Qb, bq, Mn, En, Dn, Dn, Dn, En, 0, 0, 0, 0, 0, 0, 1.0f);
    gemm_nt<0><<<dim3(En / 128, Mn / 128, 1), 256, 0, stream>>>(
        Xb, Wkb, Kb, bk, Mn, En, Dn, Dn, Dn, En, 0, 0, 0, 0, 0, 0, 1.0f);
    gemm_nt<2><<<dim3(En / 128, Mn / 128, 1), 256, 0, stream>>>(
        Xb, Wvb, Vt, bv, Mn, En, Dn, Dn, Dn, En, 0, 0, 0, 0, 0, 0, 1.0f);

    if (batched) {
        // S = scale * Q K^T for all 16 (b,h)
        gemm_nt<0><<<dim3(Sn / 128, Sn / 128, 16), 256, 0, stream>>>(
            Qb, Kb, Sb, nullptr, Sn, Sn, Dn, En, En, Sn,
            (long)Sn * En, (long)Dn, (long)Sn * En, (long)Dn,
            (long)Hn * Sn * Sn, (long)Sn * Sn, scl);
        softmax2048<<<Bn * Hn * Sn, 256, 0, stream>>>(Sb);
        // ctx = P V  (ctx reuses Q buffer)
        gemm_nt<0><<<dim3(Dn / 128, Sn / 128, 16), 256, 0, stream>>>(
            Sb, Vt, Qb, nullptr, Sn, Dn, Sn, Sn, Sn, En,
            (long)Hn * Sn * Sn, (long)Sn * Sn, (long)Hn * Dn * Sn, (long)Dn * Sn,
            (long)Sn * En, (long)Dn, 1.0f);
    } else {
        for (int z = 0; z < 16; ++z) {
            int zb = z >> 3, zh = z & 7;
            const bf16t* Az = Qb + (size_t)zb * Sn * En + (size_t)zh * Dn;
            const bf16t* Bz = Kb + (size_t)zb * Sn * En + (size_t)zh * Dn;
            gemm_nt<0><<<dim3(Sn / 128, Sn / 128, 1), 256, 0, stream>>>(
                Az, Bz, Sb, nullptr, Sn, Sn, Dn, En, En, Sn, 0, 0, 0, 0, 0, 0, scl);
            softmax2048<<<Sn, 256, 0, stream>>>(Sb);
            bf16t* Cz = Qb + (size_t)zb * Sn * En + (size_t)zh * Dn;
            gemm_nt<0><<<dim3(Dn / 128, Sn / 128, 1), 256, 0, stream>>>(
                Sb, Vt + (size_t)z * Dn * Sn, Cz, nullptr, Sn, Dn, Sn, Sn, Sn, En,
                0, 0, 0, 0, 0, 0, 1.0f);
        }
    }

    // out = ctx @ Wo^T + bo  (fp32 output)
    gemm_nt<1><<<dim3(Dn / 128, Mn / 128, 1), 256, 0, stream>>>(
        Qb, Wob, d_out, bo, Mn, Dn, En, En, En, Dn, 0, 0, 0, 0, 0, 0, 1.0f);
}

// Round 2
// 403.878 us; speedup vs baseline: 1.2421x; 1.2421x over previous
//
#include <hip/hip_runtime.h>
#include <hip/hip_bf16.h>

typedef __hip_bfloat16 bf16t;
typedef short bf16x8 __attribute__((ext_vector_type(8)));
typedef float f32x4 __attribute__((ext_vector_type(4)));

__device__ __forceinline__ float b2f(short s) {
    unsigned u = ((unsigned)(unsigned short)s) << 16;
    float f;
    __builtin_memcpy(&f, &u, 4);
    return f;
}

__device__ __forceinline__ unsigned short f2b(float f) {
    unsigned u;
    __builtin_memcpy(&u, &f, 4);
    unsigned r = (u + 0x7fffu + ((u >> 16) & 1u)) >> 16;  // RNE
    return (unsigned short)r;
}

__device__ __forceinline__ void gload_lds16(const void* g, void* l) {
    __builtin_amdgcn_global_load_lds(
        (const __attribute__((address_space(1))) void*)g,
        (__attribute__((address_space(3))) void*)l,
        16, 0, 0);
}

// ===========================================================================
// 8-phase-style NT GEMM, 256x256 tile, BK=32, 512 threads (8 waves, 2Mx4N).
// 4 K-tile LDS buffers (A:4x16KB, B:4x16KB = 128 KiB), tile t+3 staged during
// block t, counted vmcnt(8) once per K-tile (tail: 4 -> 0).
// LDS swizzle: 16B-chunk index ^= (row&3); applied via inverse-swizzled
// GLOBAL source (global_load_lds writes linearly) + swizzled ds_read.
// XCD-bijective block swizzle on the flattened grid (requires nwg%8==0,
// guarded). z-batched: z = b*8 + h.
// EPI: 0 = bf16 out (+bias, *scale); 2 = bf16 V-transposed Vt[b,h,dd,ss].
// ===========================================================================
template<int EPI>
__global__ __launch_bounds__(512, 2)
void gemm8p(const bf16t* __restrict__ Ag, const bf16t* __restrict__ Bg,
            void* __restrict__ Cg, const float* __restrict__ bias,
            int K, int lda, int ldb, int ldc,
            long aOffB, long aOffH, long bOffB, long bOffH,
            long cOffB, long cOffH, float scale)
{
    __shared__ char lds8[131072];   // A: [0,65536) 4 bufs; B: [65536,131072)

    // ---- XCD-aware bijective block swizzle over the flat grid ----
    unsigned gx = gridDim.x, gy = gridDim.y;
    unsigned nwg = gx * gy * gridDim.z;
    unsigned wg = (blockIdx.z * gy + blockIdx.y) * gx + blockIdx.x;
    if ((nwg & 7u) == 0u) wg = (wg & 7u) * (nwg >> 3) + (wg >> 3);
    const unsigned pz = wg / (gx * gy);
    const unsigned prem = wg - pz * gx * gy;
    const unsigned py = prem / gx;
    const unsigned px = prem - py * gx;

    const int zb = pz >> 3, zh = pz & 7;
    const int brow = py * 256;
    const int bcol = px * 256;

    const size_t ldab = (size_t)lda * 2;
    const size_t ldbb = (size_t)ldb * 2;
    const char* Agb = (const char*)(Ag + (size_t)zb * aOffB + (size_t)zh * aOffH)
                      + (size_t)brow * ldab;
    const char* Bgb = (const char*)(Bg + (size_t)zb * bOffB + (size_t)zh * bOffH)
                      + (size_t)bcol * ldbb;

    const int t    = threadIdx.x;
    const int lane = t & 63;
    const int wid  = t >> 6;
    const int wm   = wid >> 2;        // 0..1 : 128-row half
    const int wn   = wid & 3;         // 0..3 : 64-col quarter
    const int lr   = lane & 15;
    const int lk   = lane >> 4;

    // ---- staging source offsets (inverse-swizzled global chunks) ----
    // LDS slot s (16B chunks): row = s>>2, cl = s&3 holds global chunk cl^(row&3)
    const int srow = t >> 2;
    const int scl  = t & 3;
    const int scg  = scl ^ (srow & 3);
    const size_t aSrc = (size_t)srow * ldab + (size_t)scg * 16;
    const size_t bSrc = (size_t)srow * ldbb + (size_t)scg * 16;
    const int dst0 = t * 16;          // + 8192 for second chunk (rows +128)
    char* ldsA = lds8;
    char* ldsB = lds8 + 65536;

    // ---- ds_read addresses (swizzled chunk) ----
    const int rchunk = lk ^ (lr & 3);
    const int aByte = (wm * 128 + lr) * 64 + rchunk * 16;   // + i*1024 + buf*16384
    const int bByte = (wn * 64 + lr) * 64 + rchunk * 16;    // + j*1024 + buf*16384

    f32x4 acc[8][4];
#pragma unroll
    for (int i = 0; i < 8; ++i)
#pragma unroll
        for (int j = 0; j < 4; ++j)
            acc[i][j] = (f32x4){0.f, 0.f, 0.f, 0.f};

    const int nk = K >> 5;

#define STAGE_A(kt, bufi) do {                                              \
        const char* s_ = Agb + (size_t)(kt) * 64 + aSrc;                    \
        char* d_ = ldsA + (bufi) * 16384 + dst0;                            \
        gload_lds16(s_, d_);                                                \
        gload_lds16(s_ + 128 * ldab, d_ + 8192);                            \
    } while (0)
#define STAGE_B(kt, bufi) do {                                              \
        const char* s_ = Bgb + (size_t)(kt) * 64 + bSrc;                    \
        char* d_ = ldsB + (bufi) * 16384 + dst0;                            \
        gload_lds16(s_, d_);                                                \
        gload_lds16(s_ + 128 * ldbb, d_ + 8192);                            \
    } while (0)

    // ---- prologue: stage tiles 0..2 ----
    const int npro = nk < 3 ? nk : 3;
    for (int p = 0; p < npro; ++p) { STAGE_A(p, p & 3); STAGE_B(p, p & 3); }
    if (npro == 3) asm volatile("s_waitcnt vmcnt(8)" ::: "memory");
    else           asm volatile("s_waitcnt vmcnt(0)" ::: "memory");
    __builtin_amdgcn_s_barrier();

    for (int kt = 0; kt < nk; ++kt) {
        const int buf  = kt & 3;
        const int bufS = (kt + 3) & 3;
        const bool st  = (kt + 3) < nk;
        const char* lA = ldsA + buf * 16384;
        const char* lB = ldsB + buf * 16384;

        // ---------------- phase 1: M-frags 0-3 x N-frags 0-3 ----------------
        bf16x8 af[4], bfv[4];
#pragma unroll
        for (int i = 0; i < 4; ++i) af[i]  = *(const bf16x8*)(lA + aByte + i * 1024);
#pragma unroll
        for (int j = 0; j < 4; ++j) bfv[j] = *(const bf16x8*)(lB + bByte + j * 1024);
        if (st) STAGE_A(kt + 3, bufS);
        __builtin_amdgcn_s_barrier();
        asm volatile("s_waitcnt lgkmcnt(0)" ::: "memory");
        __builtin_amdgcn_s_setprio(1);
#pragma unroll
        for (int i = 0; i < 4; ++i)
#pragma unroll
            for (int j = 0; j < 4; ++j)
                acc[i][j] = __builtin_amdgcn_mfma_f32_16x16x32_bf16(af[i], bfv[j], acc[i][j], 0, 0, 0);
        __builtin_amdgcn_s_setprio(0);
        __builtin_amdgcn_s_barrier();

        // ---------------- phase 2: M-frags 4-7 x N-frags 0-3 ----------------
        bf16x8 af2[4];
#pragma unroll
        for (int i = 0; i < 4; ++i) af2[i] = *(const bf16x8*)(lA + aByte + (i + 4) * 1024);
        if (st) STAGE_B(kt + 3, bufS);
        if (st)                  asm volatile("s_waitcnt vmcnt(8)" ::: "memory");
        else if (kt + 2 < nk)    asm volatile("s_waitcnt vmcnt(4)" ::: "memory");
        else if (kt + 1 < nk)    asm volatile("s_waitcnt vmcnt(0)" ::: "memory");
        __builtin_amdgcn_s_barrier();
        asm volatile("s_waitcnt lgkmcnt(0)" ::: "memory");
        __builtin_amdgcn_s_setprio(1);
#pragma unroll
        for (int i = 0; i < 4; ++i)
#pragma unroll
            for (int j = 0; j < 4; ++j)
                acc[i + 4][j] = __builtin_amdgcn_mfma_f32_16x16x32_bf16(af2[i], bfv[j], acc[i + 4][j], 0, 0, 0);
        __builtin_amdgcn_s_setprio(0);
        __builtin_amdgcn_s_barrier();
    }
#undef STAGE_A
#undef STAGE_B

    // ---- epilogue ----
    if (EPI == 0) {
        unsigned short* C = (unsigned short*)((bf16t*)Cg + (size_t)zb * cOffB + (size_t)zh * cOffH);
#pragma unroll
        for (int i = 0; i < 8; ++i)
#pragma unroll
            for (int j = 0; j < 4; ++j) {
                int col = bcol + wn * 64 + j * 16 + lr;
                float badd = bias ? bias[col] : 0.f;
#pragma unroll
                for (int r = 0; r < 4; ++r) {
                    int row = brow + wm * 128 + i * 16 + lk * 4 + r;
                    C[(size_t)row * ldc + col] = f2b(acc[i][j][r] * scale + badd);
                }
            }
    } else {  // EPI == 2: Vt[((b*8+h)*512+dd)*2048 + ss]
        unsigned short* C = (unsigned short*)Cg;
#pragma unroll
        for (int i = 0; i < 8; ++i)
#pragma unroll
            for (int j = 0; j < 4; ++j) {
                int col = bcol + wn * 64 + j * 16 + lr;   // n in [0,4096)
                int hh = col >> 9, dd = col & 511;
                float badd = bias ? bias[col] : 0.f;
                int row0 = brow + wm * 128 + i * 16 + lk * 4;
                int bb = row0 >> 11, ss0 = row0 & 2047;
                ushort4 pack;
                pack.x = f2b(acc[i][j][0] * scale + badd);
                pack.y = f2b(acc[i][j][1] * scale + badd);
                pack.z = f2b(acc[i][j][2] * scale + badd);
                pack.w = f2b(acc[i][j][3] * scale + badd);
                size_t addr = ((((size_t)(bb * 8 + hh)) * 512 + dd) << 11) + (size_t)ss0;
                *(ushort4*)(C + addr) = pack;
            }
    }
}

// ===========================================================================
// m97-structure 128x128 NT GEMM kept for the output projection (N=512 would
// give only 32 blocks at 256x256). fp32 output + bias.
// ===========================================================================
__global__ __launch_bounds__(256)
void gemm_nt_f32(const bf16t* __restrict__ Ag, const bf16t* __restrict__ Bg,
                 float* __restrict__ Cg, const float* __restrict__ bias,
                 int K, int lda, int ldb, int ldc)
{
    __shared__ bf16t As[128 * 32];
    __shared__ bf16t Bs[128 * 32];

    const int t    = threadIdx.x;
    const int lane = t & 63;
    const int wid  = t >> 6;
    const int wr   = wid >> 1, wc = wid & 1;
    const int brow = blockIdx.y * 128;
    const int bcol = blockIdx.x * 128;
    const int lr   = lane & 15;
    const int lk   = lane >> 4;

    const size_t ldab = (size_t)lda * 2;
    const size_t ldbb = (size_t)ldb * 2;

    f32x4 acc[4][4];
#pragma unroll
    for (int i = 0; i < 4; ++i)
#pragma unroll
        for (int j = 0; j < 4; ++j)
            acc[i][j] = (f32x4){0.f, 0.f, 0.f, 0.f};

    const int c0 = t, c1 = t + 256;
    const char* Abase = (const char*)Ag + (size_t)brow * ldab;
    const char* Bbase = (const char*)Bg + (size_t)bcol * ldbb;
    const size_t aSrc0 = (size_t)(c0 >> 2) * ldab + (size_t)(c0 & 3) * 16;
    const size_t aSrc1 = (size_t)(c1 >> 2) * ldab + (size_t)(c1 & 3) * 16;
    const size_t bSrc0 = (size_t)(c0 >> 2) * ldbb + (size_t)(c0 & 3) * 16;
    const size_t bSrc1 = (size_t)(c1 >> 2) * ldbb + (size_t)(c1 & 3) * 16;
    char* AsB = (char*)As;
    char* BsB = (char*)Bs;

    const int nk = K >> 5;
    for (int kt = 0; kt < nk; ++kt) {
        const size_t kOff = (size_t)kt * 64;
        gload_lds16(Abase + aSrc0 + kOff, AsB + (size_t)c0 * 16);
        gload_lds16(Abase + aSrc1 + kOff, AsB + (size_t)c1 * 16);
        gload_lds16(Bbase + bSrc0 + kOff, BsB + (size_t)c0 * 16);
        gload_lds16(Bbase + bSrc1 + kOff, BsB + (size_t)c1 * 16);
        asm volatile("s_waitcnt vmcnt(0)" ::: "memory");
        __syncthreads();

        bf16x8 af[4], bfv[4];
#pragma unroll
        for (int i = 0; i < 4; ++i)
            af[i] = *(const bf16x8*)(AsB + ((size_t)(wr * 64 + i * 16 + lr) * 32 + lk * 8) * 2);
#pragma unroll
        for (int j = 0; j < 4; ++j)
            bfv[j] = *(const bf16x8*)(BsB + ((size_t)(wc * 64 + j * 16 + lr) * 32 + lk * 8) * 2);
#pragma unroll
        for (int i = 0; i < 4; ++i)
#pragma unroll
            for (int j = 0; j < 4; ++j)
                acc[i][j] = __builtin_amdgcn_mfma_f32_16x16x32_bf16(af[i], bfv[j], acc[i][j], 0, 0, 0);
        __syncthreads();
    }

    const int orow = brow + wr * 64;
    const int ocol = bcol + wc * 64;
#pragma unroll
    for (int i = 0; i < 4; ++i)
#pragma unroll
        for (int j = 0; j < 4; ++j) {
            int col = ocol + j * 16 + lr;
            float badd = bias[col];
#pragma unroll
            for (int r = 0; r < 4; ++r) {
                int row = orow + i * 16 + lk * 4 + r;
                Cg[(size_t)row * ldc + col] = acc[i][j][r] + badd;
            }
        }
}

// ---------------------------------------------------------------------------
// In-place row softmax over 2048 bf16 columns. One block (256 thr) per row.
// ---------------------------------------------------------------------------
__global__ __launch_bounds__(256)
void softmax2048(bf16t* __restrict__ Sp)
{
    size_t row = blockIdx.x;
    bf16x8* p = (bf16x8*)(Sp + row * 2048);
    int t = threadIdx.x;
    bf16x8 raw = p[t];
    float v[8];
    float mx = -3.0e38f;
#pragma unroll
    for (int i = 0; i < 8; ++i) { v[i] = b2f(raw[i]); mx = fmaxf(mx, v[i]); }
#pragma unroll
    for (int off = 1; off < 64; off <<= 1) mx = fmaxf(mx, __shfl_xor(mx, off));
    __shared__ float redm[4], reds[4];
    int wid = t >> 6, lane = t & 63;
    if (lane == 0) redm[wid] = mx;
    __syncthreads();
    mx = fmaxf(fmaxf(redm[0], redm[1]), fmaxf(redm[2], redm[3]));
    float sum = 0.f;
#pragma unroll
    for (int i = 0; i < 8; ++i) { v[i] = __expf(v[i] - mx); sum += v[i]; }
#pragma unroll
    for (int off = 1; off < 64; off <<= 1) sum += __shfl_xor(sum, off);
    if (lane == 0) reds[wid] = sum;
    __syncthreads();
    sum = reds[0] + reds[1] + reds[2] + reds[3];
    float inv = 1.0f / sum;
    bf16x8 o;
#pragma unroll
    for (int i = 0; i < 8; ++i) o[i] = (short)f2b(v[i] * inv);
    p[t] = o;
}

__global__ __launch_bounds__(256)
void cvt_f32_bf16(const float* __restrict__ in, bf16t* __restrict__ out, int n4)
{
    int i = blockIdx.x * 256 + threadIdx.x;
    if (i >= n4) return;
    float4 f = ((const float4*)in)[i];
    ushort4 o;
    o.x = f2b(f.x); o.y = f2b(f.y); o.z = f2b(f.z); o.w = f2b(f.w);
    ((ushort4*)out)[i] = o;
}

extern "C" void kernel_launch(void* const* d_in, const int* in_sizes, int n_in,
                              void* d_out, int out_size, void* d_ws, size_t ws_size,
                              hipStream_t stream)
{
    const float* x  = (const float*)d_in[0];
    const float* Wq = (const float*)d_in[1];
    const float* bq = (const float*)d_in[2];
    const float* Wk = (const float*)d_in[3];
    const float* bk = (const float*)d_in[4];
    const float* Wv = (const float*)d_in[5];
    const float* bv = (const float*)d_in[6];
    const float* Wo = (const float*)d_in[7];
    const float* bo = (const float*)d_in[8];

    const int Bn = 2, Sn = 2048, Dn = 512, Hn = 8, En = 4096;
    const int Mn = Bn * Sn;  // 4096
    const float scl = 0.044194173824159216f;  // 1/sqrt(512)

    bf16t* base = (bf16t*)d_ws;
    size_t off = 0;
    bf16t* Qb  = base + off; off += (size_t)Mn * En;   // Q, later reused as ctx
    bf16t* Kb  = base + off; off += (size_t)Mn * En;
    bf16t* Vt  = base + off; off += (size_t)Mn * En;   // [b,h,512,2048]
    bf16t* Xb  = base + off; off += (size_t)Mn * Dn;
    bf16t* Wqb = base + off; off += (size_t)En * Dn;
    bf16t* Wkb = base + off; off += (size_t)En * Dn;
    bf16t* Wvb = base + off; off += (size_t)En * Dn;
    bf16t* Wob = base + off; off += (size_t)Dn * En;
    bf16t* Sb  = base + off;

    // fp32 -> bf16
    {
        size_t nX = (size_t)Mn * Dn, nW = (size_t)En * Dn;
        cvt_f32_bf16<<<(int)(nX / 4 / 256), 256, 0, stream>>>(x,  Xb,  (int)(nX / 4));
        cvt_f32_bf16<<<(int)(nW / 4 / 256), 256, 0, stream>>>(Wq, Wqb, (int)(nW / 4));
        cvt_f32_bf16<<<(int)(nW / 4 / 256), 256, 0, stream>>>(Wk, Wkb, (int)(nW / 4));
        cvt_f32_bf16<<<(int)(nW / 4 / 256), 256, 0, stream>>>(Wv, Wvb, (int)(nW / 4));
        cvt_f32_bf16<<<(int)(nW / 4 / 256), 256, 0, stream>>>(Wo, Wob, (int)(nW / 4));
    }

    // QKV projections (M=4096, N=4096, K=512)
    gemm8p<0><<<dim3(En / 256, Mn / 256, 1), 512, 0, stream>>>(
        Xb, Wqb, Qb, bq, Dn, Dn, Dn, En, 0, 0, 0, 0, 0, 0, 1.0f);
    gemm8p<0><<<dim3(En / 256, Mn / 256, 1), 512, 0, stream>>>(
        Xb, Wkb, Kb, bk, Dn, Dn, Dn, En, 0, 0, 0, 0, 0, 0, 1.0f);
    gemm8p<2><<<dim3(En / 256, Mn / 256, 1), 512, 0, stream>>>(
        Xb, Wvb, Vt, bv, Dn, Dn, Dn, En, 0, 0, 0, 0, 0, 0, 1.0f);

    // S = scale * Q K^T for all 16 (b,h)   (M=N=2048, K=512)
    gemm8p<0><<<dim3(Sn / 256, Sn / 256, 16), 512, 0, stream>>>(
        Qb, Kb, Sb, nullptr, Dn, En, En, Sn,
        (long)Sn * En, (long)Dn, (long)Sn * En, (long)Dn,
        (long)Hn * Sn * Sn, (long)Sn * Sn, scl);

    softmax2048<<<Bn * Hn * Sn, 256, 0, stream>>>(Sb);

    // ctx = P V   (M=2048, N=512, K=2048), ctx reuses Q buffer
    gemm8p<0><<<dim3(Dn / 256, Sn / 256, 16), 512, 0, stream>>>(
        Sb, Vt, Qb, nullptr, Sn, Sn, Sn, En,
        (long)Hn * Sn * Sn, (long)Sn * Sn, (long)Hn * Dn * Sn, (long)Dn * Sn,
        (long)Sn * En, (long)Dn, 1.0f);

    // out = ctx @ Wo^T + bo  (fp32 output; M=4096, N=512, K=4096) — m97 kernel
    gemm_nt_f32<<<dim3(Dn / 128, Mn / 128, 1), 256, 0, stream>>>(
        Qb, Wob, (float*)d_out, bo, En, En, En, Dn);
}

// Round 4
// 358.121 us; speedup vs baseline: 1.4008x; 1.1278x over previous
//
#include <hip/hip_runtime.h>
#include <hip/hip_bf16.h>

typedef __hip_bfloat16 bf16t;
typedef short bf16x8 __attribute__((ext_vector_type(8)));
typedef float f32x4 __attribute__((ext_vector_type(4)));

__device__ __forceinline__ float b2f(short s) {
    unsigned u = ((unsigned)(unsigned short)s) << 16;
    float f;
    __builtin_memcpy(&f, &u, 4);
    return f;
}

__device__ __forceinline__ unsigned short f2b(float f) {
    unsigned u;
    __builtin_memcpy(&u, &f, 4);
    unsigned r = (u + 0x7fffu + ((u >> 16) & 1u)) >> 16;  // RNE
    return (unsigned short)r;
}

__device__ __forceinline__ void gload_lds16(const void* g, void* l) {
    __builtin_amdgcn_global_load_lds(
        (const __attribute__((address_space(1))) void*)g,
        (__attribute__((address_space(3))) void*)l,
        16, 0, 0);
}

// ===========================================================================
// 256x256-tile NT GEMM, BK=32, 512 threads (8 waves, 2M x 4N), 4 LDS K-tile
// buffers (128 KiB), tile t+3 staged during tile t, counted vmcnt(8).
// LDS chunk swizzle: 16B-chunk slot = chunk ^ ((row>>1)&3)  [bank-exact:
// row bits 2:1 are the ones that drop out of the bank index at 64B stride].
// Staging applies the inverse permutation on the GLOBAL source (rule #21).
// EPI 0: bf16 out (+bias,*scale) via LDS-staged coalesced store.
// EPI 2: bf16 V-transposed write Vt[b,h,dd,ss].
// ===========================================================================
template<int EPI>
__global__ __launch_bounds__(512, 2)
void gemm8p(const bf16t* __restrict__ Ag, const bf16t* __restrict__ Bg,
            void* __restrict__ Cg, const float* __restrict__ bias,
            int K, int lda, int ldb, int ldc,
            long aOffB, long aOffH, long bOffB, long bOffH,
            long cOffB, long cOffH, float scale)
{
    __shared__ __align__(16) char lds8[131072];  // A: [0,64K) ; B: [64K,128K)

    // ---- XCD-aware bijective block swizzle over the flat grid ----
    unsigned gx = gridDim.x, gy = gridDim.y;
    unsigned nwg = gx * gy * gridDim.z;
    unsigned wg = (blockIdx.z * gy + blockIdx.y) * gx + blockIdx.x;
    if ((nwg & 7u) == 0u) wg = (wg & 7u) * (nwg >> 3) + (wg >> 3);
    const unsigned pz = wg / (gx * gy);
    const unsigned prem = wg - pz * gx * gy;
    const unsigned py = prem / gx;
    const unsigned px = prem - py * gx;

    const int zb = pz >> 3, zh = pz & 7;
    const int brow = py * 256;
    const int bcol = px * 256;

    const size_t ldab = (size_t)lda * 2;
    const size_t ldbb = (size_t)ldb * 2;
    const char* Agb = (const char*)(Ag + (size_t)zb * aOffB + (size_t)zh * aOffH)
                      + (size_t)brow * ldab;
    const char* Bgb = (const char*)(Bg + (size_t)zb * bOffB + (size_t)zh * bOffH)
                      + (size_t)bcol * ldbb;

    const int t    = threadIdx.x;
    const int lane = t & 63;
    const int wid  = t >> 6;
    const int wm   = wid >> 2;        // 0..1 : 128-row half
    const int wn   = wid & 3;         // 0..3 : 64-col quarter
    const int lr   = lane & 15;
    const int lk   = lane >> 4;

    // ---- staging: thread t covers chunk t (row t>>2, slot t&3) and chunk
    // t+512 (row +128). Source chunk = slot ^ ((row>>1)&3); rows +128 keep
    // the same swizzle ((128>>1)&3 == 0).
    const int srow = t >> 2;
    const int scg  = (t & 3) ^ ((srow >> 1) & 3);
    const size_t aSrc = (size_t)srow * ldab + (size_t)scg * 16;
    const size_t bSrc = (size_t)srow * ldbb + (size_t)scg * 16;
    const int dst0 = t * 16;
    char* ldsA = lds8;
    char* ldsB = lds8 + 65536;

    // ---- ds_read addresses (swizzled chunk slot) ----
    const int rchunk = lk ^ ((lr >> 1) & 3);
    const int aByte = (wm * 128 + lr) * 64 + rchunk * 16;   // + i*1024 + buf*16384
    const int bByte = (wn * 64 + lr) * 64 + rchunk * 16;    // + j*1024 + buf*16384

    f32x4 acc[8][4];
#pragma unroll
    for (int i = 0; i < 8; ++i)
#pragma unroll
        for (int j = 0; j < 4; ++j)
            acc[i][j] = (f32x4){0.f, 0.f, 0.f, 0.f};

    const int nk = K >> 5;

#define STAGE_A(kt, bufi) do {                                              \
        const char* s_ = Agb + (size_t)(kt) * 64 + aSrc;                    \
        char* d_ = ldsA + (bufi) * 16384 + dst0;                            \
        gload_lds16(s_, d_);                                                \
        gload_lds16(s_ + 128 * ldab, d_ + 8192);                            \
    } while (0)
#define STAGE_B(kt, bufi) do {                                              \
        const char* s_ = Bgb + (size_t)(kt) * 64 + bSrc;                    \
        char* d_ = ldsB + (bufi) * 16384 + dst0;                            \
        gload_lds16(s_, d_);                                                \
        gload_lds16(s_ + 128 * ldbb, d_ + 8192);                            \
    } while (0)

    // ---- prologue: stage tiles 0..2 ----
    const int npro = nk < 3 ? nk : 3;
    for (int p = 0; p < npro; ++p) { STAGE_A(p, p & 3); STAGE_B(p, p & 3); }
    if (npro == 3) asm volatile("s_waitcnt vmcnt(8)" ::: "memory");
    else           asm volatile("s_waitcnt vmcnt(0)" ::: "memory");
    __builtin_amdgcn_s_barrier();

    for (int kt = 0; kt < nk; ++kt) {
        const int buf  = kt & 3;
        const int bufS = (kt + 3) & 3;
        const bool st  = (kt + 3) < nk;
        const char* lA = ldsA + buf * 16384;
        const char* lB = ldsB + buf * 16384;

        // -------- phase 1: M-frags 0-3 x N-frags 0-3 --------
        bf16x8 af[4], bfv[4];
#pragma unroll
        for (int i = 0; i < 4; ++i) af[i]  = *(const bf16x8*)(lA + aByte + i * 1024);
#pragma unroll
        for (int j = 0; j < 4; ++j) bfv[j] = *(const bf16x8*)(lB + bByte + j * 1024);
        if (st) STAGE_A(kt + 3, bufS);
        __builtin_amdgcn_s_barrier();
        asm volatile("s_waitcnt lgkmcnt(0)" ::: "memory");
        __builtin_amdgcn_s_setprio(1);
#pragma unroll
        for (int i = 0; i < 4; ++i)
#pragma unroll
            for (int j = 0; j < 4; ++j)
                acc[i][j] = __builtin_amdgcn_mfma_f32_16x16x32_bf16(af[i], bfv[j], acc[i][j], 0, 0, 0);
        __builtin_amdgcn_s_setprio(0);
        __builtin_amdgcn_s_barrier();

        // -------- phase 2: M-frags 4-7 x N-frags 0-3 --------
        bf16x8 af2[4];
#pragma unroll
        for (int i = 0; i < 4; ++i) af2[i] = *(const bf16x8*)(lA + aByte + (i + 4) * 1024);
        if (st) STAGE_B(kt + 3, bufS);
        if (st)                  asm volatile("s_waitcnt vmcnt(8)" ::: "memory");
        else if (kt + 2 < nk)    asm volatile("s_waitcnt vmcnt(4)" ::: "memory");
        else if (kt + 1 < nk)    asm volatile("s_waitcnt vmcnt(0)" ::: "memory");
        __builtin_amdgcn_s_barrier();
        asm volatile("s_waitcnt lgkmcnt(0)" ::: "memory");
        __builtin_amdgcn_s_setprio(1);
#pragma unroll
        for (int i = 0; i < 4; ++i)
#pragma unroll
            for (int j = 0; j < 4; ++j)
                acc[i + 4][j] = __builtin_amdgcn_mfma_f32_16x16x32_bf16(af2[i], bfv[j], acc[i + 4][j], 0, 0, 0);
        __builtin_amdgcn_s_setprio(0);
        __builtin_amdgcn_s_barrier();
    }
#undef STAGE_A
#undef STAGE_B

    // ---- epilogue ----
    if (EPI == 0) {
        // Stage the 256x256 bf16 C-tile in LDS, then fully-coalesced 16B writes.
        __syncthreads();   // all K-loop LDS reads done; safe to overwrite
        unsigned short* lC = (unsigned short*)lds8;
#pragma unroll
        for (int i = 0; i < 8; ++i)
#pragma unroll
            for (int j = 0; j < 4; ++j) {
                int col = wn * 64 + j * 16 + lr;
                float badd = bias ? bias[bcol + col] : 0.f;
#pragma unroll
                for (int r = 0; r < 4; ++r) {
                    int row = wm * 128 + i * 16 + lk * 4 + r;
                    lC[row * 256 + col] = f2b(acc[i][j][r] * scale + badd);
                }
            }
        __syncthreads();
        unsigned short* C = (unsigned short*)((bf16t*)Cg + (size_t)zb * cOffB + (size_t)zh * cOffH);
#pragma unroll
        for (int p = 0; p < 16; ++p) {
            int c  = p * 512 + t;        // 16B chunk index, 8192 total
            int row = c >> 5;            // 32 chunks per 256-col row
            int cc  = c & 31;
            bf16x8 v = *(const bf16x8*)(lC + (size_t)c * 8);
            *(bf16x8*)(C + (size_t)(brow + row) * ldc + bcol + cc * 8) = v;
        }
    } else {  // EPI == 2: Vt[((b*8+h)*512+dd)*2048 + ss]
        unsigned short* C = (unsigned short*)Cg;
#pragma unroll
        for (int i = 0; i < 8; ++i)
#pragma unroll
            for (int j = 0; j < 4; ++j) {
                int col = bcol + wn * 64 + j * 16 + lr;   // n in [0,4096)
                int hh = col >> 9, dd = col & 511;
                float badd = bias ? bias[col] : 0.f;
                int row0 = brow + wm * 128 + i * 16 + lk * 4;
                int bb = row0 >> 11, ss0 = row0 & 2047;
                ushort4 pack;
                pack.x = f2b(acc[i][j][0] * scale + badd);
                pack.y = f2b(acc[i][j][1] * scale + badd);
                pack.z = f2b(acc[i][j][2] * scale + badd);
                pack.w = f2b(acc[i][j][3] * scale + badd);
                size_t addr = ((((size_t)(bb * 8 + hh)) * 512 + dd) << 11) + (size_t)ss0;
                *(ushort4*)(C + addr) = pack;
            }
    }
}

// ===========================================================================
// Output projection: 128x64-tile NT GEMM (fp32 out + bias), 256 threads,
// 4 waves (2x2, wave tile 64x32). Grid 8x32 = 256 blocks = full GPU.
// Same corrected chunk swizzle; small LDS (12 KiB) -> high occupancy.
// ===========================================================================
__global__ __launch_bounds__(256)
void gemm_of32(const bf16t* __restrict__ Ag, const bf16t* __restrict__ Bg,
               float* __restrict__ Cg, const float* __restrict__ bias,
               int K, int lda, int ldb, int ldc)
{
    __shared__ __align__(16) bf16t As[128 * 32];
    __shared__ __align__(16) bf16t Bs[64 * 32];

    unsigned gx = gridDim.x, gy = gridDim.y;
    unsigned nwg = gx * gy;
    unsigned wg = blockIdx.y * gx + blockIdx.x;
    if ((nwg & 7u) == 0u) wg = (wg & 7u) * (nwg >> 3) + (wg >> 3);
    const unsigned py = wg / gx;
    const unsigned px = wg - py * gx;
    const int brow = py * 128;
    const int bcol = px * 64;

    const int t    = threadIdx.x;
    const int lane = t & 63;
    const int wid  = t >> 6;
    const int wr   = wid >> 1, wc = wid & 1;
    const int lr   = lane & 15;
    const int lk   = lane >> 4;

    const size_t ldab = (size_t)lda * 2;
    const size_t ldbb = (size_t)ldb * 2;

    f32x4 acc[4][2];
#pragma unroll
    for (int i = 0; i < 4; ++i)
#pragma unroll
        for (int j = 0; j < 2; ++j)
            acc[i][j] = (f32x4){0.f, 0.f, 0.f, 0.f};

    // staging: A = 512 chunks (2/thread), B = 256 chunks (1/thread)
    const int srow = t >> 2;
    const int scg  = (t & 3) ^ ((srow >> 1) & 3);
    const char* Abase = (const char*)Ag + (size_t)brow * ldab;
    const char* Bbase = (const char*)Bg + (size_t)bcol * ldbb;
    const size_t aSrc = (size_t)srow * ldab + (size_t)scg * 16;
    const size_t bSrc = (size_t)srow * ldbb + (size_t)scg * 16;
    char* AsB = (char*)As;
    char* BsB = (char*)Bs;

    const int rchunk = lk ^ ((lr >> 1) & 3);
    const int aByte = (wr * 64 + lr) * 64 + rchunk * 16;   // + i*1024
    const int bByte = (wc * 32 + lr) * 64 + rchunk * 16;   // + j*1024

    const int nk = K >> 5;
    for (int kt = 0; kt < nk; ++kt) {
        const size_t kOff = (size_t)kt * 64;
        gload_lds16(Abase + aSrc + kOff,             AsB + t * 16);
        gload_lds16(Abase + aSrc + 64 * ldab + kOff, AsB + t * 16 + 4096);
        gload_lds16(Bbase + bSrc + kOff,             BsB + t * 16);
        asm volatile("s_waitcnt vmcnt(0)" ::: "memory");
        __syncthreads();

        bf16x8 af[4], bfv[2];
#pragma unroll
        for (int i = 0; i < 4; ++i)
            af[i] = *(const bf16x8*)(AsB + aByte + i * 1024);
#pragma unroll
        for (int j = 0; j < 2; ++j)
            bfv[j] = *(const bf16x8*)(BsB + bByte + j * 1024);
#pragma unroll
        for (int i = 0; i < 4; ++i)
#pragma unroll
            for (int j = 0; j < 2; ++j)
                acc[i][j] = __builtin_amdgcn_mfma_f32_16x16x32_bf16(af[i], bfv[j], acc[i][j], 0, 0, 0);
        __syncthreads();
    }

    const int orow = brow + wr * 64;
    const int ocol = bcol + wc * 32;
#pragma unroll
    for (int i = 0; i < 4; ++i)
#pragma unroll
        for (int j = 0; j < 2; ++j) {
            int col = ocol + j * 16 + lr;
            float badd = bias[col];
#pragma unroll
            for (int r = 0; r < 4; ++r) {
                int row = orow + i * 16 + lk * 4 + r;
                Cg[(size_t)row * ldc + col] = acc[i][j][r] + badd;
            }
        }
}

// ---------------------------------------------------------------------------
// In-place row softmax over 2048 bf16 columns. One block (256 thr) per row.
// ---------------------------------------------------------------------------
__global__ __launch_bounds__(256)
void softmax2048(bf16t* __restrict__ Sp)
{
    size_t row = blockIdx.x;
    bf16x8* p = (bf16x8*)(Sp + row * 2048);
    int t = threadIdx.x;
    bf16x8 raw = p[t];
    float v[8];
    float mx = -3.0e38f;
#pragma unroll
    for (int i = 0; i < 8; ++i) { v[i] = b2f(raw[i]); mx = fmaxf(mx, v[i]); }
#pragma unroll
    for (int off = 1; off < 64; off <<= 1) mx = fmaxf(mx, __shfl_xor(mx, off));
    __shared__ float redm[4], reds[4];
    int wid = t >> 6, lane = t & 63;
    if (lane == 0) redm[wid] = mx;
    __syncthreads();
    mx = fmaxf(fmaxf(redm[0], redm[1]), fmaxf(redm[2], redm[3]));
    float sum = 0.f;
#pragma unroll
    for (int i = 0; i < 8; ++i) { v[i] = __expf(v[i] - mx); sum += v[i]; }
#pragma unroll
    for (int off = 1; off < 64; off <<= 1) sum += __shfl_xor(sum, off);
    if (lane == 0) reds[wid] = sum;
    __syncthreads();
    sum = reds[0] + reds[1] + reds[2] + reds[3];
    float inv = 1.0f / sum;
    bf16x8 o;
#pragma unroll
    for (int i = 0; i < 8; ++i) o[i] = (short)f2b(v[i] * inv);
    p[t] = o;
}

// ---------------------------------------------------------------------------
// One-shot fp32 -> bf16 for all five tensors (equal sizes: 2M elements each).
// ---------------------------------------------------------------------------
__global__ __launch_bounds__(256)
void cvt5(const float* __restrict__ s0, const float* __restrict__ s1,
          const float* __restrict__ s2, const float* __restrict__ s3,
          const float* __restrict__ s4,
          bf16t* __restrict__ d0, bf16t* __restrict__ d1,
          bf16t* __restrict__ d2, bf16t* __restrict__ d3,
          bf16t* __restrict__ d4)
{
    const float* s;
    bf16t* d;
    switch (blockIdx.y) {
        case 0: s = s0; d = d0; break;
        case 1: s = s1; d = d1; break;
        case 2: s = s2; d = d2; break;
        case 3: s = s3; d = d3; break;
        default: s = s4; d = d4; break;
    }
    int i = blockIdx.x * 256 + threadIdx.x;
    float4 f = ((const float4*)s)[i];
    ushort4 o;
    o.x = f2b(f.x); o.y = f2b(f.y); o.z = f2b(f.z); o.w = f2b(f.w);
    ((ushort4*)d)[i] = o;
}

extern "C" void kernel_launch(void* const* d_in, const int* in_sizes, int n_in,
                              void* d_out, int out_size, void* d_ws, size_t ws_size,
                              hipStream_t stream)
{
    const float* x  = (const float*)d_in[0];
    const float* Wq = (const float*)d_in[1];
    const float* bq = (const float*)d_in[2];
    const float* Wk = (const float*)d_in[3];
    const float* bk = (const float*)d_in[4];
    const float* Wv = (const float*)d_in[5];
    const float* bv = (const float*)d_in[6];
    const float* Wo = (const float*)d_in[7];
    const float* bo = (const float*)d_in[8];

    const int Bn = 2, Sn = 2048, Dn = 512, Hn = 8, En = 4096;
    const int Mn = Bn * Sn;  // 4096
    const float scl = 0.044194173824159216f;  // 1/sqrt(512)

    bf16t* base = (bf16t*)d_ws;
    size_t off = 0;
    bf16t* Qb  = base + off; off += (size_t)Mn * En;   // Q, later reused as ctx
    bf16t* Kb  = base + off; off += (size_t)Mn * En;
    bf16t* Vt  = base + off; off += (size_t)Mn * En;   // [b,h,512,2048]
    bf16t* Xb  = base + off; off += (size_t)Mn * Dn;
    bf16t* Wqb = base + off; off += (size_t)En * Dn;
    bf16t* Wkb = base + off; off += (size_t)En * Dn;
    bf16t* Wvb = base + off; off += (size_t)En * Dn;
    bf16t* Wob = base + off; off += (size_t)Dn * En;
    bf16t* Sb  = base + off;

    // fp32 -> bf16 (five 2M-element tensors, one launch)
    cvt5<<<dim3(2048, 5, 1), 256, 0, stream>>>(x, Wq, Wk, Wv, Wo,
                                               Xb, Wqb, Wkb, Wvb, Wob);

    // QKV projections (M=4096, N=4096, K=512)
    gemm8p<0><<<dim3(En / 256, Mn / 256, 1), 512, 0, stream>>>(
        Xb, Wqb, Qb, bq, Dn, Dn, Dn, En, 0, 0, 0, 0, 0, 0, 1.0f);
    gemm8p<0><<<dim3(En / 256, Mn / 256, 1), 512, 0, stream>>>(
        Xb, Wkb, Kb, bk, Dn, Dn, Dn, En, 0, 0, 0, 0, 0, 0, 1.0f);
    gemm8p<2><<<dim3(En / 256, Mn / 256, 1), 512, 0, stream>>>(
        Xb, Wvb, Vt, bv, Dn, Dn, Dn, En, 0, 0, 0, 0, 0, 0, 1.0f);

    // S = scale * Q K^T for all 16 (b,h)   (M=N=2048, K=512)
    gemm8p<0><<<dim3(Sn / 256, Sn / 256, 16), 512, 0, stream>>>(
        Qb, Kb, Sb, nullptr, Dn, En, En, Sn,
        (long)Sn * En, (long)Dn, (long)Sn * En, (long)Dn,
        (long)Hn * Sn * Sn, (long)Sn * Sn, scl);

    softmax2048<<<Bn * Hn * Sn, 256, 0, stream>>>(Sb);

    // ctx = P V   (M=2048, N=512, K=2048), ctx reuses Q buffer
    gemm8p<0><<<dim3(Dn / 256, Sn / 256, 16), 512, 0, stream>>>(
        Sb, Vt, Qb, nullptr, Sn, Sn, Sn, En,
        (long)Hn * Sn * Sn, (long)Sn * Sn, (long)Hn * Dn * Sn, (long)Dn * Sn,
        (long)Sn * En, (long)Dn, 1.0f);

    // out = ctx @ Wo^T + bo  (fp32; M=4096, N=512, K=4096)
    gemm_of32<<<dim3(Dn / 64, Mn / 128, 1), 256, 0, stream>>>(
        Qb, Wob, (float*)d_out, bo, En, En, En, Dn);
}

// Round 5
// 300.002 us; speedup vs baseline: 1.6722x; 1.1937x over previous
//
#include <hip/hip_runtime.h>
#include <hip/hip_bf16.h>

typedef __hip_bfloat16 bf16t;
typedef short bf16x8 __attribute__((ext_vector_type(8)));
typedef float f32x4 __attribute__((ext_vector_type(4)));

__device__ __forceinline__ float b2f(short s) {
    unsigned u = ((unsigned)(unsigned short)s) << 16;
    float f;
    __builtin_memcpy(&f, &u, 4);
    return f;
}

__device__ __forceinline__ unsigned short f2b(float f) {
    unsigned u;
    __builtin_memcpy(&u, &f, 4);
    unsigned r = (u + 0x7fffu + ((u >> 16) & 1u)) >> 16;  // RNE
    return (unsigned short)r;
}

__device__ __forceinline__ void gload_lds16(const void* g, void* l) {
    __builtin_amdgcn_global_load_lds(
        (const __attribute__((address_space(1))) void*)g,
        (__attribute__((address_space(3))) void*)l,
        16, 0, 0);
}

// ===========================================================================
// 256x256-tile NT GEMM, BK=32, 512 threads (8 waves, 2M x 4N), 4 LDS K-tile
// buffers (128 KiB), tile t+3 staged during tile t, counted vmcnt(8).
// Schedule: per K-tile 2 phases, each {ds_read subtile; stage; MFMA
// (compiler-counted lgkmcnt); trailing barrier}. No forced lgkm drains,
// no leading barriers (quad-buffer makes them unnecessary: every read of a
// buffer is register-consumed before that phase's trailing barrier, and a
// stage targets a buffer last read >=2 barriers earlier).
// LDS chunk swizzle: slot = chunk ^ ((row>>1)&3), inverse applied on the
// global source (global_load_lds writes linearly).
// EPI 0: bf16 out (+bias, *scale) via LDS-staged coalesced store.
// EPI 2: bf16 V-transposed write Vt[b,h,dd,ss].
// EPI 3: bf16 out scaled per-row by 1/rowsum (PV normalize), reads part.
// EPI 4: bf16 out = exp(scale*acc), writes partial rowsums to part.
// ===========================================================================
template<int EPI>
__global__ __launch_bounds__(512, 2)
void gemm8p(const bf16t* __restrict__ Ag, const bf16t* __restrict__ Bg,
            void* __restrict__ Cg, const float* __restrict__ bias,
            float* __restrict__ part,
            int K, int lda, int ldb, int ldc,
            long aOffB, long aOffH, long bOffB, long bOffH,
            long cOffB, long cOffH, float scale)
{
    __shared__ __align__(16) char lds8[131072];  // A: [0,64K) ; B: [64K,128K)

    // ---- XCD-aware bijective block swizzle over the flat grid ----
    unsigned gx = gridDim.x, gy = gridDim.y;
    unsigned nwg = gx * gy * gridDim.z;
    unsigned wg = (blockIdx.z * gy + blockIdx.y) * gx + blockIdx.x;
    if ((nwg & 7u) == 0u) wg = (wg & 7u) * (nwg >> 3) + (wg >> 3);
    const unsigned pz = wg / (gx * gy);
    const unsigned prem = wg - pz * gx * gy;
    const unsigned py = prem / gx;
    const unsigned px = prem - py * gx;

    const int zb = pz >> 3, zh = pz & 7;
    const int brow = py * 256;
    const int bcol = px * 256;

    const size_t ldab = (size_t)lda * 2;
    const size_t ldbb = (size_t)ldb * 2;
    const char* Agb = (const char*)(Ag + (size_t)zb * aOffB + (size_t)zh * aOffH)
                      + (size_t)brow * ldab;
    const char* Bgb = (const char*)(Bg + (size_t)zb * bOffB + (size_t)zh * bOffH)
                      + (size_t)bcol * ldbb;

    const int t    = threadIdx.x;
    const int lane = t & 63;
    const int wid  = t >> 6;
    const int wm   = wid >> 2;        // 0..1 : 128-row half
    const int wn   = wid & 3;         // 0..3 : 64-col quarter
    const int lr   = lane & 15;
    const int lk   = lane >> 4;

    // staging: thread t covers chunk t (row t>>2, slot t&3) and chunk t+512
    // (row +128, same swizzle since (128>>1)&3 == 0).
    const int srow = t >> 2;
    const int scg  = (t & 3) ^ ((srow >> 1) & 3);
    const size_t aSrc = (size_t)srow * ldab + (size_t)scg * 16;
    const size_t bSrc = (size_t)srow * ldbb + (size_t)scg * 16;
    const int dst0 = t * 16;
    char* ldsA = lds8;
    char* ldsB = lds8 + 65536;

    // ds_read addresses (swizzled chunk slot)
    const int rchunk = lk ^ ((lr >> 1) & 3);
    const int aByte = (wm * 128 + lr) * 64 + rchunk * 16;   // + i*1024 + buf*16384
    const int bByte = (wn * 64 + lr) * 64 + rchunk * 16;    // + j*1024 + buf*16384

    f32x4 acc[8][4];
#pragma unroll
    for (int i = 0; i < 8; ++i)
#pragma unroll
        for (int j = 0; j < 4; ++j)
            acc[i][j] = (f32x4){0.f, 0.f, 0.f, 0.f};

    const int nk = K >> 5;

#define STAGE_A(kt, bufi) do {                                              \
        const char* s_ = Agb + (size_t)(kt) * 64 + aSrc;                    \
        char* d_ = ldsA + (bufi) * 16384 + dst0;                            \
        gload_lds16(s_, d_);                                                \
        gload_lds16(s_ + 128 * ldab, d_ + 8192);                            \
    } while (0)
#define STAGE_B(kt, bufi) do {                                              \
        const char* s_ = Bgb + (size_t)(kt) * 64 + bSrc;                    \
        char* d_ = ldsB + (bufi) * 16384 + dst0;                            \
        gload_lds16(s_, d_);                                                \
        gload_lds16(s_ + 128 * ldbb, d_ + 8192);                            \
    } while (0)

    // ---- prologue: stage tiles 0..2 ----
    const int npro = nk < 3 ? nk : 3;
    for (int p = 0; p < npro; ++p) { STAGE_A(p, p & 3); STAGE_B(p, p & 3); }
    if (npro == 3) asm volatile("s_waitcnt vmcnt(8)" ::: "memory");
    else           asm volatile("s_waitcnt vmcnt(0)" ::: "memory");
    __builtin_amdgcn_s_barrier();

    for (int kt = 0; kt < nk; ++kt) {
        const int buf  = kt & 3;
        const int bufS = (kt + 3) & 3;
        const bool st  = (kt + 3) < nk;
        const char* lA = ldsA + buf * 16384;
        const char* lB = ldsB + buf * 16384;

        // -------- phase 1: M-frags 0-3 x N-frags 0-3 --------
        bf16x8 af[4], bfv[4];
#pragma unroll
        for (int i = 0; i < 4; ++i) af[i]  = *(const bf16x8*)(lA + aByte + i * 1024);
#pragma unroll
        for (int j = 0; j < 4; ++j) bfv[j] = *(const bf16x8*)(lB + bByte + j * 1024);
        if (st) STAGE_A(kt + 3, bufS);
        __builtin_amdgcn_s_setprio(1);
#pragma unroll
        for (int i = 0; i < 4; ++i)
#pragma unroll
            for (int j = 0; j < 4; ++j)
                acc[i][j] = __builtin_amdgcn_mfma_f32_16x16x32_bf16(af[i], bfv[j], acc[i][j], 0, 0, 0);
        __builtin_amdgcn_s_setprio(0);
        asm volatile("" ::: "memory");
        __builtin_amdgcn_s_barrier();

        // -------- phase 2: M-frags 4-7 x N-frags 0-3 --------
        bf16x8 af2[4];
#pragma unroll
        for (int i = 0; i < 4; ++i) af2[i] = *(const bf16x8*)(lA + aByte + (i + 4) * 1024);
        if (st) STAGE_B(kt + 3, bufS);
        if (st)                  asm volatile("s_waitcnt vmcnt(8)" ::: "memory");
        else if (kt + 2 < nk)    asm volatile("s_waitcnt vmcnt(4)" ::: "memory");
        else if (kt + 1 < nk)    asm volatile("s_waitcnt vmcnt(0)" ::: "memory");
        __builtin_amdgcn_s_setprio(1);
#pragma unroll
        for (int i = 0; i < 4; ++i)
#pragma unroll
            for (int j = 0; j < 4; ++j)
                acc[i + 4][j] = __builtin_amdgcn_mfma_f32_16x16x32_bf16(af2[i], bfv[j], acc[i + 4][j], 0, 0, 0);
        __builtin_amdgcn_s_setprio(0);
        asm volatile("" ::: "memory");
        __builtin_amdgcn_s_barrier();
    }
#undef STAGE_A
#undef STAGE_B

    // ---- epilogues ----
    if (EPI == 4) {
        // E = exp(scale * s); partial rowsums over this block's 256 cols.
#pragma unroll
        for (int i = 0; i < 8; ++i)
#pragma unroll
            for (int j = 0; j < 4; ++j)
#pragma unroll
                for (int r = 0; r < 4; ++r)
                    acc[i][j][r] = __expf(acc[i][j][r] * scale);
        // rowsum partials: reduce over j (4 cols spots) then lr (16 lanes);
        // lanes lr==0 hold the wave's 64-col partial for row (wm,i,lk,r).
#pragma unroll
        for (int i = 0; i < 8; ++i)
#pragma unroll
            for (int r = 0; r < 4; ++r) {
                float v = acc[i][0][r] + acc[i][1][r] + acc[i][2][r] + acc[i][3][r];
                v += __shfl_xor(v, 1);
                v += __shfl_xor(v, 2);
                v += __shfl_xor(v, 4);
                v += __shfl_xor(v, 8);
                if (lr == 0)
                    part[((size_t)pz * 2048 + brow + wm * 128 + i * 16 + lk * 4 + r) * 32
                         + px * 4 + wn] = v;
            }
        // coalesced E write via LDS staging
        __syncthreads();
        unsigned short* lC = (unsigned short*)lds8;
#pragma unroll
        for (int i = 0; i < 8; ++i)
#pragma unroll
            for (int j = 0; j < 4; ++j) {
                int col = wn * 64 + j * 16 + lr;
#pragma unroll
                for (int r = 0; r < 4; ++r) {
                    int row = wm * 128 + i * 16 + lk * 4 + r;
                    lC[row * 256 + col] = f2b(acc[i][j][r]);
                }
            }
        __syncthreads();
        unsigned short* C = (unsigned short*)((bf16t*)Cg + (size_t)zb * cOffB + (size_t)zh * cOffH);
#pragma unroll
        for (int p = 0; p < 16; ++p) {
            int c  = p * 512 + t;
            int row = c >> 5;
            int cc  = c & 31;
            bf16x8 v = *(const bf16x8*)(lC + (size_t)c * 8);
            *(bf16x8*)(C + (size_t)(brow + row) * ldc + bcol + cc * 8) = v;
        }
    } else if (EPI == 3) {
        // per-row normalization by 1/sum(part[row][0..32))
        __syncthreads();
        float* ldsInv = (float*)lds8;
        if (t < 256) {
            const float* pp = part + ((size_t)pz * 2048 + brow + t) * 32;
            float s = 0.f;
#pragma unroll
            for (int p = 0; p < 32; ++p) s += pp[p];
            ldsInv[t] = 1.0f / s;
        }
        __syncthreads();
        float linv[8][4];
#pragma unroll
        for (int i = 0; i < 8; ++i)
#pragma unroll
            for (int r = 0; r < 4; ++r)
                linv[i][r] = ldsInv[wm * 128 + i * 16 + lk * 4 + r];
        __syncthreads();
        unsigned short* lC = (unsigned short*)lds8;
#pragma unroll
        for (int i = 0; i < 8; ++i)
#pragma unroll
            for (int j = 0; j < 4; ++j) {
                int col = wn * 64 + j * 16 + lr;
#pragma unroll
                for (int r = 0; r < 4; ++r) {
                    int row = wm * 128 + i * 16 + lk * 4 + r;
                    lC[row * 256 + col] = f2b(acc[i][j][r] * linv[i][r]);
                }
            }
        __syncthreads();
        unsigned short* C = (unsigned short*)((bf16t*)Cg + (size_t)zb * cOffB + (size_t)zh * cOffH);
#pragma unroll
        for (int p = 0; p < 16; ++p) {
            int c  = p * 512 + t;
            int row = c >> 5;
            int cc  = c & 31;
            bf16x8 v = *(const bf16x8*)(lC + (size_t)c * 8);
            *(bf16x8*)(C + (size_t)(brow + row) * ldc + bcol + cc * 8) = v;
        }
    } else if (EPI == 0) {
        __syncthreads();
        unsigned short* lC = (unsigned short*)lds8;
#pragma unroll
        for (int i = 0; i < 8; ++i)
#pragma unroll
            for (int j = 0; j < 4; ++j) {
                int col = wn * 64 + j * 16 + lr;
                float badd = bias ? bias[bcol + col] : 0.f;
#pragma unroll
                for (int r = 0; r < 4; ++r) {
                    int row = wm * 128 + i * 16 + lk * 4 + r;
                    lC[row * 256 + col] = f2b(acc[i][j][r] * scale + badd);
                }
            }
        __syncthreads();
        unsigned short* C = (unsigned short*)((bf16t*)Cg + (size_t)zb * cOffB + (size_t)zh * cOffH);
#pragma unroll
        for (int p = 0; p < 16; ++p) {
            int c  = p * 512 + t;
            int row = c >> 5;
            int cc  = c & 31;
            bf16x8 v = *(const bf16x8*)(lC + (size_t)c * 8);
            *(bf16x8*)(C + (size_t)(brow + row) * ldc + bcol + cc * 8) = v;
        }
    } else {  // EPI == 2: Vt[((b*8+h)*512+dd)*2048 + ss]
        unsigned short* C = (unsigned short*)Cg;
#pragma unroll
        for (int i = 0; i < 8; ++i)
#pragma unroll
            for (int j = 0; j < 4; ++j) {
                int col = bcol + wn * 64 + j * 16 + lr;   // n in [0,4096)
                int hh = col >> 9, dd = col & 511;
                float badd = bias ? bias[col] : 0.f;
                int row0 = brow + wm * 128 + i * 16 + lk * 4;
                int bb = row0 >> 11, ss0 = row0 & 2047;
                ushort4 pack;
                pack.x = f2b(acc[i][j][0] * scale + badd);
                pack.y = f2b(acc[i][j][1] * scale + badd);
                pack.z = f2b(acc[i][j][2] * scale + badd);
                pack.w = f2b(acc[i][j][3] * scale + badd);
                size_t addr = ((((size_t)(bb * 8 + hh)) * 512 + dd) << 11) + (size_t)ss0;
                *(ushort4*)(C + addr) = pack;
            }
    }
}

// ===========================================================================
// Output projection: 128x64-tile NT GEMM (fp32 out + bias), 256 threads,
// 4 waves (2x2, wave tile 64x32), quad-buffered (48 KiB LDS -> 3 blocks/CU),
// counted vmcnt(6), one barrier per K-tile.
// ===========================================================================
__global__ __launch_bounds__(256, 3)
void gemm_of32(const bf16t* __restrict__ Ag, const bf16t* __restrict__ Bg,
               float* __restrict__ Cg, const float* __restrict__ bias,
               int K, int lda, int ldb, int ldc)
{
    __shared__ __align__(16) char lds[49152];  // A: 4x8KB at 0; B: 4x4KB at 32768

    unsigned gx = gridDim.x, gy = gridDim.y;
    unsigned nwg = gx * gy;
    unsigned wg = blockIdx.y * gx + blockIdx.x;
    if ((nwg & 7u) == 0u) wg = (wg & 7u) * (nwg >> 3) + (wg >> 3);
    const unsigned py = wg / gx;
    const unsigned px = wg - py * gx;
    const int brow = py * 128;
    const int bcol = px * 64;

    const int t    = threadIdx.x;
    const int lane = t & 63;
    const int wid  = t >> 6;
    const int wr   = wid >> 1, wc = wid & 1;
    const int lr   = lane & 15;
    const int lk   = lane >> 4;

    const size_t ldab = (size_t)lda * 2;
    const size_t ldbb = (size_t)ldb * 2;
    const char* Agb = (const char*)Ag + (size_t)brow * ldab;
    const char* Bgb = (const char*)Bg + (size_t)bcol * ldbb;

    const int srow = t >> 2;                       // A rows [0,64) per round
    const int scg  = (t & 3) ^ ((srow >> 1) & 3);
    const size_t aSrc = (size_t)srow * ldab + (size_t)scg * 16;
    const size_t bSrc = (size_t)srow * ldbb + (size_t)scg * 16;
    char* ldsA = lds;
    char* ldsB = lds + 32768;

    const int rchunk = lk ^ ((lr >> 1) & 3);
    const int aByte = (wr * 64 + lr) * 64 + rchunk * 16;   // + i*1024 + buf*8192
    const int bByte = (wc * 32 + lr) * 64 + rchunk * 16;   // + j*1024 + buf*4096

    f32x4 acc[4][2];
#pragma unroll
    for (int i = 0; i < 4; ++i)
#pragma unroll
        for (int j = 0; j < 2; ++j)
            acc[i][j] = (f32x4){0.f, 0.f, 0.f, 0.f};

    const int nk = K >> 5;

#define STAGE_O(kt, bufi) do {                                              \
        const char* sa_ = Agb + (size_t)(kt) * 64 + aSrc;                   \
        gload_lds16(sa_,             ldsA + (bufi) * 8192 + t * 16);        \
        gload_lds16(sa_ + 64 * ldab, ldsA + (bufi) * 8192 + 4096 + t * 16); \
        gload_lds16(Bgb + (size_t)(kt) * 64 + bSrc,                         \
                    ldsB + (bufi) * 4096 + t * 16);                         \
    } while (0)

    for (int p = 0; p < 3; ++p) STAGE_O(p, p);
    asm volatile("s_waitcnt vmcnt(6)" ::: "memory");
    __builtin_amdgcn_s_barrier();

    for (int kt = 0; kt < nk; ++kt) {
        const int buf  = kt & 3;
        const bool st  = (kt + 3) < nk;
        const char* lA = ldsA + buf * 8192;
        const char* lB = ldsB + buf * 4096;

        bf16x8 af[4], bfv[2];
#pragma unroll
        for (int i = 0; i < 4; ++i) af[i]  = *(const bf16x8*)(lA + aByte + i * 1024);
#pragma unroll
        for (int j = 0; j < 2; ++j) bfv[j] = *(const bf16x8*)(lB + bByte + j * 1024);
        if (st) STAGE_O(kt + 3, (kt + 3) & 3);
        if (st)                  asm volatile("s_waitcnt vmcnt(6)" ::: "memory");
        else if (kt + 2 < nk)    asm volatile("s_waitcnt vmcnt(3)" ::: "memory");
        else if (kt + 1 < nk)    asm volatile("s_waitcnt vmcnt(0)" ::: "memory");
        __builtin_amdgcn_s_setprio(1);
#pragma unroll
        for (int i = 0; i < 4; ++i)
#pragma unroll
            for (int j = 0; j < 2; ++j)
                acc[i][j] = __builtin_amdgcn_mfma_f32_16x16x32_bf16(af[i], bfv[j], acc[i][j], 0, 0, 0);
        __builtin_amdgcn_s_setprio(0);
        asm volatile("" ::: "memory");
        __builtin_amdgcn_s_barrier();
    }
#undef STAGE_O

    const int orow = brow + wr * 64;
    const int ocol = bcol + wc * 32;
#pragma unroll
    for (int i = 0; i < 4; ++i)
#pragma unroll
        for (int j = 0; j < 2; ++j) {
            int col = ocol + j * 16 + lr;
            float badd = bias[col];
#pragma unroll
            for (int r = 0; r < 4; ++r) {
                int row = orow + i * 16 + lk * 4 + r;
                Cg[(size_t)row * ldc + col] = acc[i][j][r] + badd;
            }
        }
}

// ---------------------------------------------------------------------------
// One-shot fp32 -> bf16 for all five tensors (equal sizes: 2M elements each).
// ---------------------------------------------------------------------------
__global__ __launch_bounds__(256)
void cvt5(const float* __restrict__ s0, const float* __restrict__ s1,
          const float* __restrict__ s2, const float* __restrict__ s3,
          const float* __restrict__ s4,
          bf16t* __restrict__ d0, bf16t* __restrict__ d1,
          bf16t* __restrict__ d2, bf16t* __restrict__ d3,
          bf16t* __restrict__ d4)
{
    const float* s;
    bf16t* d;
    switch (blockIdx.y) {
        case 0: s = s0; d = d0; break;
        case 1: s = s1; d = d1; break;
        case 2: s = s2; d = d2; break;
        case 3: s = s3; d = d3; break;
        default: s = s4; d = d4; break;
    }
    int i = blockIdx.x * 256 + threadIdx.x;
    float4 f = ((const float4*)s)[i];
    ushort4 o;
    o.x = f2b(f.x); o.y = f2b(f.y); o.z = f2b(f.z); o.w = f2b(f.w);
    ((ushort4*)d)[i] = o;
}

extern "C" void kernel_launch(void* const* d_in, const int* in_sizes, int n_in,
                              void* d_out, int out_size, void* d_ws, size_t ws_size,
                              hipStream_t stream)
{
    const float* x  = (const float*)d_in[0];
    const float* Wq = (const float*)d_in[1];
    const float* bq = (const float*)d_in[2];
    const float* Wk = (const float*)d_in[3];
    const float* bk = (const float*)d_in[4];
    const float* Wv = (const float*)d_in[5];
    const float* bv = (const float*)d_in[6];
    const float* Wo = (const float*)d_in[7];
    const float* bo = (const float*)d_in[8];

    const int Bn = 2, Sn = 2048, Dn = 512, Hn = 8, En = 4096;
    const int Mn = Bn * Sn;  // 4096
    const float scl = 0.044194173824159216f;  // 1/sqrt(512)

    bf16t* base = (bf16t*)d_ws;
    size_t off = 0;
    bf16t* Qb  = base + off; off += (size_t)Mn * En;   // Q, later reused as ctx
    bf16t* Kb  = base + off; off += (size_t)Mn * En;
    bf16t* Vt  = base + off; off += (size_t)Mn * En;   // [b,h,512,2048]
    bf16t* Xb  = base + off; off += (size_t)Mn * Dn;
    bf16t* Wqb = base + off; off += (size_t)En * Dn;
    bf16t* Wkb = base + off; off += (size_t)En * Dn;
    bf16t* Wvb = base + off; off += (size_t)En * Dn;
    bf16t* Wob = base + off; off += (size_t)Dn * En;
    float* Pt  = (float*)(base + off); off += (size_t)16 * Sn * 32 * 2;  // 4MB rowsum partials
    bf16t* Sb  = base + off;

    // fp32 -> bf16 (five 2M-element tensors, one launch)
    cvt5<<<dim3(2048, 5, 1), 256, 0, stream>>>(x, Wq, Wk, Wv, Wo,
                                               Xb, Wqb, Wkb, Wvb, Wob);

    // QKV projections (M=4096, N=4096, K=512)
    gemm8p<0><<<dim3(En / 256, Mn / 256, 1), 512, 0, stream>>>(
        Xb, Wqb, Qb, bq, nullptr, Dn, Dn, Dn, En, 0, 0, 0, 0, 0, 0, 1.0f);
    gemm8p<0><<<dim3(En / 256, Mn / 256, 1), 512, 0, stream>>>(
        Xb, Wkb, Kb, bk, nullptr, Dn, Dn, Dn, En, 0, 0, 0, 0, 0, 0, 1.0f);
    gemm8p<2><<<dim3(En / 256, Mn / 256, 1), 512, 0, stream>>>(
        Xb, Wvb, Vt, bv, nullptr, Dn, Dn, Dn, En, 0, 0, 0, 0, 0, 0, 1.0f);

    // E = exp(scale * Q K^T) for all 16 (b,h) + partial rowsums
    gemm8p<4><<<dim3(Sn / 256, Sn / 256, 16), 512, 0, stream>>>(
        Qb, Kb, Sb, nullptr, Pt, Dn, En, En, Sn,
        (long)Sn * En, (long)Dn, (long)Sn * En, (long)Dn,
        (long)Hn * Sn * Sn, (long)Sn * Sn, scl);

    // ctx = (E V) / rowsum   (M=2048, N=512, K=2048), ctx reuses Q buffer
    gemm8p<3><<<dim3(Dn / 256, Sn / 256, 16), 512, 0, stream>>>(
        Sb, Vt, Qb, nullptr, Pt, Sn, Sn, Sn, En,
        (long)Hn * Sn * Sn, (long)Sn * Sn, (long)Hn * Dn * Sn, (long)Dn * Sn,
        (long)Sn * En, (long)Dn, 1.0f);

    // out = ctx @ Wo^T + bo  (fp32; M=4096, N=512, K=4096)
    gemm_of32<<<dim3(Dn / 64, Mn / 128, 1), 256, 0, stream>>>(
        Qb, Wob, (float*)d_out, bo, En, En, En, Dn);
}